// Round 8
// baseline (139.968 us; speedup 1.0000x reference)
//
#include <hip/hip_runtime.h>
#include <math.h>

#define NN 50000
#define NE 800000
#define NH 4
#define HD 32
#define FD 128   // NH*HD == IN_DIM
#define NTILE 3125  // 50000 / 16 exactly

typedef __attribute__((ext_vector_type(8))) short short8;
typedef __attribute__((ext_vector_type(4))) float floatx4;

__device__ __forceinline__ unsigned short f2bf(float f) {
    union { float f; unsigned u; } v; v.f = f;
    unsigned u = v.u;
    return (unsigned short)((u + 0x7FFFu + ((u >> 16) & 1u)) >> 16);
}
__device__ __forceinline__ float bf_lo(unsigned u) {
    union { unsigned u; float f; } v; v.u = u << 16; return v.f;
}
__device__ __forceinline__ float bf_hi(unsigned u) {
    union { unsigned u; float f; } v; v.u = u & 0xFFFF0000u; return v.f;
}

// ---------------------------------------------------------------------------
// Kernel 1: projection via bf16 MFMA, fused node-attention epilogue (shuffle
// reduction from fp32 accumulators — R4-verified) and fused CSR row-offset
// construction from sorted dst (independent grid-stride tail).
// ---------------------------------------------------------------------------
__global__ __launch_bounds__(512) void k_gemm_fused(const float* __restrict__ x,
                                                    const float* __restrict__ W,
                                                    const float* __restrict__ al,
                                                    const float* __restrict__ ar,
                                                    const int* __restrict__ dst,
                                                    unsigned short* __restrict__ feat_bf,
                                                    float* __restrict__ el,
                                                    float* __restrict__ er,
                                                    int* __restrict__ rows) {
    __shared__ unsigned short Wl[FD * 136];   // Wl[c][k], row stride 136 bf16
    const int tid = threadIdx.x;

    for (int p = tid; p < FD * 64; p += 512) {
        int c = p >> 6, k2 = (p & 63) * 2;
        float2 wv = *(const float2*)&W[c * FD + k2];
        *(unsigned*)&Wl[c * 136 + k2] =
            (unsigned)f2bf(wv.x) | ((unsigned)f2bf(wv.y) << 16);
    }
    __syncthreads();

    const int wv_id = tid >> 6, lane = tid & 63;
    const int col = lane & 15, quad = lane >> 4;

    // attention vectors for this lane's 8 output cols (col + 16*ct)
    float alr[8], arr[8];
    #pragma unroll
    for (int ct = 0; ct < 8; ++ct) {
        alr[ct] = al[col + 16 * ct];
        arr[ct] = ar[col + 16 * ct];
    }

    for (int tile = blockIdx.x * 8 + wv_id; tile < NTILE; tile += gridDim.x * 8) {
        const int n0 = tile * 16;

        short8 afrag[4];
        const float* xrow = x + (size_t)(n0 + col) * FD;
        #pragma unroll
        for (int s = 0; s < 4; ++s) {
            float4 u0 = *(const float4*)&xrow[s * 32 + quad * 8];
            float4 u1 = *(const float4*)&xrow[s * 32 + quad * 8 + 4];
            short8 a;
            a[0] = (short)f2bf(u0.x); a[1] = (short)f2bf(u0.y);
            a[2] = (short)f2bf(u0.z); a[3] = (short)f2bf(u0.w);
            a[4] = (short)f2bf(u1.x); a[5] = (short)f2bf(u1.y);
            a[6] = (short)f2bf(u1.z); a[7] = (short)f2bf(u1.w);
            afrag[s] = a;
        }

        floatx4 acc[8];
        #pragma unroll
        for (int ct = 0; ct < 8; ++ct) acc[ct] = (floatx4){0.f, 0.f, 0.f, 0.f};

        #pragma unroll
        for (int ct = 0; ct < 8; ++ct) {
            #pragma unroll
            for (int s = 0; s < 4; ++s) {
                short8 b = *(const short8*)&Wl[(ct * 16 + col) * 136 + s * 32 + quad * 8];
                acc[ct] = __builtin_amdgcn_mfma_f32_16x16x32_bf16(afrag[s], b, acc[ct], 0, 0, 0);
            }
        }

        // feat store (C/D: col = lane&15, row = quad*4 + reg)
        #pragma unroll
        for (int ct = 0; ct < 8; ++ct) {
            #pragma unroll
            for (int r = 0; r < 4; ++r) {
                feat_bf[(size_t)(n0 + quad * 4 + r) * FD + ct * 16 + col] = f2bf(acc[ct][r]);
            }
        }

        // fused el/er: head h owns cols 32h..32h+31 = lane cols ct in {2h, 2h+1}
        #pragma unroll
        for (int r = 0; r < 4; ++r) {
            float ev[8];
            #pragma unroll
            for (int hh = 0; hh < NH; ++hh) {
                ev[hh]     = acc[2 * hh][r] * alr[2 * hh] + acc[2 * hh + 1][r] * alr[2 * hh + 1];
                ev[4 + hh] = acc[2 * hh][r] * arr[2 * hh] + acc[2 * hh + 1][r] * arr[2 * hh + 1];
            }
            #pragma unroll
            for (int m = 1; m < 16; m <<= 1) {
                #pragma unroll
                for (int j = 0; j < 8; ++j) ev[j] += __shfl_xor(ev[j], m);
            }
            if (col == 0) {
                int n = n0 + quad * 4 + r;
                *(float4*)&el[n * NH] = make_float4(ev[0], ev[1], ev[2], ev[3]);
                *(float4*)&er[n * NH] = make_float4(ev[4], ev[5], ev[6], ev[7]);
            }
        }
    }

    // CSR rows from sorted dst (independent of GEMM data)
    const int gsz = gridDim.x * 512;
    for (int i = blockIdx.x * 512 + tid; i < NE; i += gsz) {
        int cur = dst[i];
        if (i == 0) {
            for (int n = 0; n <= cur; ++n) rows[n] = 0;
        } else {
            int prev = dst[i - 1];
            for (int n = prev + 1; n <= cur; ++n) rows[n] = i;
        }
        if (i == NE - 1) {
            for (int n = cur + 1; n <= NN; ++n) rows[n] = NE;
        }
    }
}

// ---------------------------------------------------------------------------
// Kernel 2: fused edge-softmax + aggregation (R4 structure + inline exp).
// One wave per node; 4 edge slots x 16 dim lanes, x4 unroll -> 16 edges
// (32 cache lines) in flight. w = exp(leakyrelu(el[src]+er[n])) computed
// inline — el table is 0.8 MB (L2-resident), unshifted exp is exact-safe
// (logits sigma ~0.23). Tail edges masked with w=0.
// ---------------------------------------------------------------------------
__global__ __launch_bounds__(256) void k_aggregate(const unsigned short* __restrict__ feat_bf,
                                                   const float* __restrict__ el,
                                                   const float* __restrict__ er,
                                                   const int* __restrict__ src,
                                                   const int* __restrict__ rows,
                                                   float* __restrict__ out) {
    const int wave = threadIdx.x >> 6;
    const int lane = threadIdx.x & 63;
    const int n = blockIdx.x * 4 + wave;
    if (n >= NN) return;

    const int s = rows[n], t = rows[n + 1];
    const int q  = lane >> 4;        // edge slot 0..3
    const int lp = lane & 15;        // dim slot: dims 8*lp .. 8*lp+7
    const int h  = lp >> 2;          // head of those dims
    const int dimoff = 8 * lp;

    const float erh = er[n * NH + h];

    float acc[8] = {0.f, 0.f, 0.f, 0.f, 0.f, 0.f, 0.f, 0.f};
    float den = 0.f;

    for (int e = s; e < t; e += 16) {
        int sjv[4];
        #pragma unroll
        for (int u = 0; u < 4; ++u) {
            int ei = e + 4 * u + q;
            sjv[u] = src[(ei < t) ? ei : (t - 1)];
        }
        float elv[4];
        #pragma unroll
        for (int u = 0; u < 4; ++u) elv[u] = el[sjv[u] * NH + h];
        uint4 uvv[4];
        #pragma unroll
        for (int u = 0; u < 4; ++u)
            uvv[u] = *(const uint4*)&feat_bf[(size_t)sjv[u] * FD + dimoff];
        #pragma unroll
        for (int u = 0; u < 4; ++u) {
            int ei = e + 4 * u + q;
            float lg = elv[u] + erh;
            float z  = fmaxf(lg, 0.2f * lg);
            float w  = (ei < t) ? __expf(z) : 0.f;
            uint4 uv = uvv[u];
            acc[0] += w * bf_lo(uv.x); acc[1] += w * bf_hi(uv.x);
            acc[2] += w * bf_lo(uv.y); acc[3] += w * bf_hi(uv.y);
            acc[4] += w * bf_lo(uv.z); acc[5] += w * bf_hi(uv.z);
            acc[6] += w * bf_lo(uv.w); acc[7] += w * bf_hi(uv.w);
            den += w;
        }
    }

    // combine the 4 edge-slot groups (lanes differing in bits 4,5)
    #pragma unroll
    for (int m = 16; m < 64; m <<= 1) {
        #pragma unroll
        for (int j = 0; j < 8; ++j) acc[j] += __shfl_xor(acc[j], m);
        den += __shfl_xor(den, m);
    }

    if (q == 0) {
        const float rden = (den > 0.f) ? 1.f / den : 0.f;
        float* op = out + (size_t)n * FD + dimoff;
        *(float4*)op       = make_float4(acc[0] * rden, acc[1] * rden, acc[2] * rden, acc[3] * rden);
        *(float4*)(op + 4) = make_float4(acc[4] * rden, acc[5] * rden, acc[6] * rden, acc[7] * rden);
    }
}

// ---------------------------------------------------------------------------
extern "C" void kernel_launch(void* const* d_in, const int* in_sizes, int n_in,
                              void* d_out, int out_size, void* d_ws, size_t ws_size,
                              hipStream_t stream) {
    const float* x  = (const float*)d_in[0];
    const float* W  = (const float*)d_in[1];
    const float* al = (const float*)d_in[2];
    const float* ar = (const float*)d_in[3];
    const int* src  = (const int*)d_in[4];
    const int* dst  = (const int*)d_in[5];
    float* out = (float*)d_out;

    // ws: feat_bf[NN*FD] ushort | el[NN*NH] | er[NN*NH] | rows[NN+1]
    unsigned short* feat_bf = (unsigned short*)d_ws;
    float* el = (float*)(feat_bf + (size_t)NN * FD);
    float* er = el + (size_t)NN * NH;
    int*   rows = (int*)(er + (size_t)NN * NH);

    k_gemm_fused<<<256, 512, 0, stream>>>(x, W, al, ar, dst, feat_bf, el, er, rows);
    k_aggregate<<<(NN + 3) / 4, 256, 0, stream>>>(feat_bf, el, er, src, rows, out);
}

// Round 9
// 135.509 us; speedup vs baseline: 1.0329x; 1.0329x over previous
//
#include <hip/hip_runtime.h>
#include <math.h>

#define NN 50000
#define NE 800000
#define NH 4
#define HD 32
#define FD 128   // NH*HD == IN_DIM
#define NTILE 3125  // 50000 / 16 exactly

typedef __attribute__((ext_vector_type(8))) short short8;
typedef __attribute__((ext_vector_type(4))) float floatx4;

__device__ __forceinline__ unsigned short f2bf(float f) {
    union { float f; unsigned u; } v; v.f = f;
    unsigned u = v.u;
    return (unsigned short)((u + 0x7FFFu + ((u >> 16) & 1u)) >> 16);
}
__device__ __forceinline__ float bf_lo(unsigned u) {
    union { unsigned u; float f; } v; v.u = u << 16; return v.f;
}
__device__ __forceinline__ float bf_hi(unsigned u) {
    union { unsigned u; float f; } v; v.u = u & 0xFFFF0000u; return v.f;
}

// ---------------------------------------------------------------------------
// Kernel 1: projection via bf16 MFMA, fused node-attention epilogue
// (shuffle reduction from fp32 accumulators). R4-identical.
// ---------------------------------------------------------------------------
__global__ __launch_bounds__(512) void k_gemm_fused(const float* __restrict__ x,
                                                    const float* __restrict__ W,
                                                    const float* __restrict__ al,
                                                    const float* __restrict__ ar,
                                                    unsigned short* __restrict__ feat_bf,
                                                    float* __restrict__ el,
                                                    float* __restrict__ er) {
    __shared__ unsigned short Wl[FD * 136];   // Wl[c][k], row stride 136 bf16
    const int tid = threadIdx.x;

    for (int p = tid; p < FD * 64; p += 512) {
        int c = p >> 6, k2 = (p & 63) * 2;
        float2 wv = *(const float2*)&W[c * FD + k2];
        *(unsigned*)&Wl[c * 136 + k2] =
            (unsigned)f2bf(wv.x) | ((unsigned)f2bf(wv.y) << 16);
    }
    __syncthreads();

    const int wv_id = tid >> 6, lane = tid & 63;
    const int col = lane & 15, quad = lane >> 4;

    // attention vectors for this lane's 8 output cols (col + 16*ct)
    float alr[8], arr[8];
    #pragma unroll
    for (int ct = 0; ct < 8; ++ct) {
        alr[ct] = al[col + 16 * ct];
        arr[ct] = ar[col + 16 * ct];
    }

    for (int tile = blockIdx.x * 8 + wv_id; tile < NTILE; tile += gridDim.x * 8) {
        const int n0 = tile * 16;

        short8 afrag[4];
        const float* xrow = x + (size_t)(n0 + col) * FD;
        #pragma unroll
        for (int s = 0; s < 4; ++s) {
            float4 u0 = *(const float4*)&xrow[s * 32 + quad * 8];
            float4 u1 = *(const float4*)&xrow[s * 32 + quad * 8 + 4];
            short8 a;
            a[0] = (short)f2bf(u0.x); a[1] = (short)f2bf(u0.y);
            a[2] = (short)f2bf(u0.z); a[3] = (short)f2bf(u0.w);
            a[4] = (short)f2bf(u1.x); a[5] = (short)f2bf(u1.y);
            a[6] = (short)f2bf(u1.z); a[7] = (short)f2bf(u1.w);
            afrag[s] = a;
        }

        floatx4 acc[8];
        #pragma unroll
        for (int ct = 0; ct < 8; ++ct) acc[ct] = (floatx4){0.f, 0.f, 0.f, 0.f};

        #pragma unroll
        for (int ct = 0; ct < 8; ++ct) {
            #pragma unroll
            for (int s = 0; s < 4; ++s) {
                short8 b = *(const short8*)&Wl[(ct * 16 + col) * 136 + s * 32 + quad * 8];
                acc[ct] = __builtin_amdgcn_mfma_f32_16x16x32_bf16(afrag[s], b, acc[ct], 0, 0, 0);
            }
        }

        // feat store (C/D: col = lane&15, row = quad*4 + reg)
        #pragma unroll
        for (int ct = 0; ct < 8; ++ct) {
            #pragma unroll
            for (int r = 0; r < 4; ++r) {
                feat_bf[(size_t)(n0 + quad * 4 + r) * FD + ct * 16 + col] = f2bf(acc[ct][r]);
            }
        }

        // fused el/er: head h owns cols 32h..32h+31 = lane cols ct in {2h, 2h+1}
        #pragma unroll
        for (int r = 0; r < 4; ++r) {
            float ev[8];
            #pragma unroll
            for (int hh = 0; hh < NH; ++hh) {
                ev[hh]     = acc[2 * hh][r] * alr[2 * hh] + acc[2 * hh + 1][r] * alr[2 * hh + 1];
                ev[4 + hh] = acc[2 * hh][r] * arr[2 * hh] + acc[2 * hh + 1][r] * arr[2 * hh + 1];
            }
            #pragma unroll
            for (int m = 1; m < 16; m <<= 1) {
                #pragma unroll
                for (int j = 0; j < 8; ++j) ev[j] += __shfl_xor(ev[j], m);
            }
            if (col == 0) {
                int n = n0 + quad * 4 + r;
                *(float4*)&el[n * NH] = make_float4(ev[0], ev[1], ev[2], ev[3]);
                *(float4*)&er[n * NH] = make_float4(ev[4], ev[5], ev[6], ev[7]);
            }
        }
    }
}

// ---------------------------------------------------------------------------
// Kernel 2: per-edge softmax numerators, EDGE-MAJOR wE[e][h] (float4/edge),
// fused CSR row-offset construction from sorted dst. R4-identical.
// ---------------------------------------------------------------------------
__global__ void k_edgew(const float* __restrict__ el,
                        const float* __restrict__ er,
                        const int* __restrict__ src,
                        const int* __restrict__ dst,
                        float* __restrict__ wE,
                        int* __restrict__ rows) {
    int e = blockIdx.x * blockDim.x + threadIdx.x;
    if (e >= NE) return;
    int sj = src[e], dj = dst[e];

    // CSR boundaries
    if (e == 0) {
        for (int n = 0; n <= dj; ++n) rows[n] = 0;
    } else {
        int prev = dst[e - 1];
        for (int n = prev + 1; n <= dj; ++n) rows[n] = e;
    }
    if (e == NE - 1) {
        for (int n = dj + 1; n <= NN; ++n) rows[n] = NE;
    }

    float4 el4 = *(const float4*)&el[sj * NH];
    float4 er4 = *(const float4*)&er[dj * NH];
    float4 w;
    float lg, z;
    lg = el4.x + er4.x; z = fmaxf(lg, 0.2f * lg); w.x = __expf(z);
    lg = el4.y + er4.y; z = fmaxf(lg, 0.2f * lg); w.y = __expf(z);
    lg = el4.z + er4.z; z = fmaxf(lg, 0.2f * lg); w.z = __expf(z);
    lg = el4.w + er4.w; z = fmaxf(lg, 0.2f * lg); w.w = __expf(z);
    *(float4*)&wE[e * NH] = w;
}

// ---------------------------------------------------------------------------
// Kernel 3: aggregation (R4 structure). One wave per node; 4 edge slots x
// 16 dim lanes, x4 unroll -> 16 edges (32 cache lines) in flight. Tail edges
// masked with w=0. ONLY change vs R4: NT hints on streamed-once src/wE loads
// and the out store, so they don't evict feat lines from L2.
// ---------------------------------------------------------------------------
__global__ __launch_bounds__(256) void k_aggregate(const unsigned short* __restrict__ feat_bf,
                                                   const float* __restrict__ wE,
                                                   const int* __restrict__ src,
                                                   const int* __restrict__ rows,
                                                   float* __restrict__ out) {
    const int wave = threadIdx.x >> 6;
    const int lane = threadIdx.x & 63;
    const int n = blockIdx.x * 4 + wave;
    if (n >= NN) return;

    const int s = rows[n], t = rows[n + 1];
    const int q  = lane >> 4;        // edge slot 0..3
    const int lp = lane & 15;        // dim slot: dims 8*lp .. 8*lp+7
    const int h  = lp >> 2;          // head of those dims
    const int dimoff = 8 * lp;

    float acc[8] = {0.f, 0.f, 0.f, 0.f, 0.f, 0.f, 0.f, 0.f};
    float den = 0.f;

    for (int e = s; e < t; e += 16) {
        int   sjv[4];
        float wv4[4];
        #pragma unroll
        for (int u = 0; u < 4; ++u) {
            int ei = e + 4 * u + q;
            int ec = (ei < t) ? ei : (t - 1);
            sjv[u] = __builtin_nontemporal_load(&src[ec]);
            wv4[u] = (ei < t) ? __builtin_nontemporal_load(&wE[ec * NH + h]) : 0.f;
        }
        uint4 uvv[4];
        #pragma unroll
        for (int u = 0; u < 4; ++u)
            uvv[u] = *(const uint4*)&feat_bf[(size_t)sjv[u] * FD + dimoff];
        #pragma unroll
        for (int u = 0; u < 4; ++u) {
            float w = wv4[u];
            uint4 uv = uvv[u];
            acc[0] += w * bf_lo(uv.x); acc[1] += w * bf_hi(uv.x);
            acc[2] += w * bf_lo(uv.y); acc[3] += w * bf_hi(uv.y);
            acc[4] += w * bf_lo(uv.z); acc[5] += w * bf_hi(uv.z);
            acc[6] += w * bf_lo(uv.w); acc[7] += w * bf_hi(uv.w);
            den += w;
        }
    }

    // combine the 4 edge-slot groups (lanes differing in bits 4,5)
    #pragma unroll
    for (int m = 16; m < 64; m <<= 1) {
        #pragma unroll
        for (int j = 0; j < 8; ++j) acc[j] += __shfl_xor(acc[j], m);
        den += __shfl_xor(den, m);
    }

    if (q == 0) {
        const float rden = (den > 0.f) ? 1.f / den : 0.f;
        float* op = out + (size_t)n * FD + dimoff;
        #pragma unroll
        for (int j = 0; j < 8; ++j)
            __builtin_nontemporal_store(acc[j] * rden, op + j);
    }
}

// ---------------------------------------------------------------------------
extern "C" void kernel_launch(void* const* d_in, const int* in_sizes, int n_in,
                              void* d_out, int out_size, void* d_ws, size_t ws_size,
                              hipStream_t stream) {
    const float* x  = (const float*)d_in[0];
    const float* W  = (const float*)d_in[1];
    const float* al = (const float*)d_in[2];
    const float* ar = (const float*)d_in[3];
    const int* src  = (const int*)d_in[4];
    const int* dst  = (const int*)d_in[5];
    float* out = (float*)d_out;

    // ws: feat_bf[NN*FD] ushort | el[NN*NH] | er[NN*NH] | rows[NN+1] | wE[NE*NH]
    unsigned short* feat_bf = (unsigned short*)d_ws;
    float* el = (float*)(feat_bf + (size_t)NN * FD);
    float* er = el + (size_t)NN * NH;
    int*   rows = (int*)(er + (size_t)NN * NH);
    float* wE = (float*)(((uintptr_t)(rows + NN + 1) + 15) & ~(uintptr_t)15);

    k_gemm_fused<<<256, 512, 0, stream>>>(x, W, al, ar, feat_bf, el, er);
    k_edgew<<<(NE + 255) / 256, 256, 0, stream>>>(el, er, src, dst, wE, rows);
    k_aggregate<<<(NN + 3) / 4, 256, 0, stream>>>(feat_bf, wE, src, rows, out);
}